// Round 7
// baseline (899.695 us; speedup 1.0000x reference)
//
#include <hip/hip_runtime.h>

#define VOX (128*128*32)   // 524288 voxels
#define CCH 64
#define NCL 20
#define DD 128
#define HH 128
#define WW 32
#define ZT 16
#define EPSV 1e-5f
#define THRESV 0.2f

// ---- order-preserving float <-> uint key for atomic min/max ----
__device__ __forceinline__ unsigned keyOf(float f){
    unsigned u = __float_as_uint(f);
    return (u & 0x80000000u) ? ~u : (u | 0x80000000u);
}
__device__ __forceinline__ float keyInv(unsigned k){
    unsigned u = (k & 0x80000000u) ? (k & 0x7fffffffu) : ~k;
    return __uint_as_float(u);
}

__global__ void k_init(unsigned* keys, float* zpg){
    int i = threadIdx.x;
    if (i < NCL){ keys[i] = 0xFFFFFFFFu; keys[NCL+i] = 0u; }
    #pragma unroll
    for (int k = 0; k < 4; ++k) zpg[k*64 + i] = 0.f;
}

// ---- Pass A: logit (einsum + bias), softmax masks, per-voxel mean/max over C ----
__global__ __launch_bounds__(256) void k_logit_softmax(
    const float* __restrict__ x, const float* __restrict__ clsw,
    const float* __restrict__ clsb, float* __restrict__ masks,
    float* __restrict__ logit, float* __restrict__ mx, float* __restrict__ Mx)
{
    __shared__ float sw[NCL*CCH];
    __shared__ float sb[NCL];
    int tid = threadIdx.x;
    for (int q = tid; q < NCL*CCH; q += 256) sw[q] = clsw[q];
    if (tid < NCL) sb[tid] = clsb[tid];
    __syncthreads();
    int v = blockIdx.x*256 + tid;
    float acc[NCL];
    #pragma unroll
    for (int o=0;o<NCL;o++) acc[o] = sb[o];
    float s = 0.f, mm = -1e30f;
    for (int c=0;c<CCH;c++){
        float xv = x[c*VOX + v];
        s += xv; mm = fmaxf(mm, xv);
        #pragma unroll
        for (int o=0;o<NCL;o++) acc[o] = fmaf(xv, sw[o*CCH + c], acc[o]);
    }
    mx[v] = s * (1.f/64.f);
    Mx[v] = mm;
    float lm = acc[0];
    #pragma unroll
    for (int o=1;o<NCL;o++) lm = fmaxf(lm, acc[o]);
    float es = 0.f;
    #pragma unroll
    for (int o=0;o<NCL;o++){
        logit[o*VOX + v] = acc[o];
        float e = expf(acc[o] - lm);
        es += e; acc[o] = e;
    }
    float inv = 1.f/es;
    #pragma unroll
    for (int o=0;o<NCL;o++) masks[o*VOX + v] = acc[o]*inv;
}

// ---- Pass B: z-marching FIR conv, async double-buffered LDS, exact counted vmcnt ----
// block = 128 thr (2 waves): y = tid>>3 (16 rows), x0 = (tid&7)*4 (4 outputs).
// grid = (20 cls, 8 z, 8 y) = 1280 blocks; LDS 18.4KB -> 8 blocks/CU = 16 waves/CU.
// Slice = 3 raw planes (mask,mx,Mx) of [22 rows x 32], quad-XOR swizzled, padded to 2304 fl.
// 9 global_load_lds(16B)/slice: wave0 issues 5, wave1 4 -> exact vmcnt(L or L+1).
// OOB lanes read a zero page (full EXEC -> counts provable). Store AFTER issue_slice.

#define F4(A, WV, q0,q1,q2,q3) { A.x=fmaf(q0,WV,A.x); A.y=fmaf(q1,WV,A.y); \
                                 A.z=fmaf(q2,WV,A.z); A.w=fmaf(q3,WV,A.w); }
#define DZ4(A, WP, P) { \
    F4(A,(WP)[0], P##0,P##1,P##2,P##3) \
    F4(A,(WP)[1], P##1,P##2,P##3,P##4) \
    F4(A,(WP)[2], P##2,P##3,P##4,P##5) \
    F4(A,(WP)[3], P##3,P##4,P##5,P##6) \
    F4(A,(WP)[4], P##4,P##5,P##6,P##7) \
    F4(A,(WP)[5], P##5,P##6,P##7,P##8) \
    F4(A,(WP)[6], P##6,P##7,P##8,P##9) }

#define TGROUP4(P, WT) { \
    const float* wd_ = (WT) + dy*7; \
    if (ok6) DZ4(a6, wd_+0,   P) \
    if (ok5) DZ4(a5, wd_+49,  P) \
    if (ok4) DZ4(a4, wd_+98,  P) \
    if (ok3) DZ4(a3, wd_+147, P) \
    if (ok2) DZ4(a2, wd_+196, P) \
    if (ok1) DZ4(a1, wd_+245, P) \
    if (ok0) DZ4(a0, wd_+294, P) }

#define PLANE_F 704      // 22 rows x 32 floats
#define SLICE_Q 528      // real granules (3 planes x 176)
#define BUF_F   2304     // padded slice floats (9 issues x 256)
#define LDS_F   4608     // 2 buffers

__device__ __forceinline__ void issue_slice(const float* mk, const float* mxp, const float* Mxp,
        const float* zpg, float* FLf, int bufF, int zi, int y0, int lane, int wid)
{
    const bool zok = (unsigned)zi < (unsigned)DD;
    const float* srcs[3] = { mk, mxp, Mxp };
    #pragma unroll
    for (int i = 0; i < 9; ++i){
        if ((i < 5) != (wid == 0)) continue;     // wave0: 5 issues, wave1: 4
        int q = i*64 + lane;
        const float* g;
        if (q < SLICE_Q && zok){
            int f   = q / 176;
            int r   = q - f*176;
            int row = r >> 3, xq = r & 7;
            int gy  = y0 - 3 + row;
            if ((unsigned)gy < (unsigned)HH)
                g = srcs[f] + (((size_t)(zi*HH + gy)*8 + (xq ^ (row & 7))) << 2);
            else
                g = zpg + lane*4;
        } else {
            g = zpg + lane*4;
        }
        float* l = FLf + bufF + i*256;           // wave-uniform; HW adds lane*16B
        __builtin_amdgcn_global_load_lds(
            (const __attribute__((address_space(1))) void*)g,
            (__attribute__((address_space(3))) void*)l, 16, 0, 0);
    }
}

__global__ __launch_bounds__(128, 4) void k_conv7(const float* __restrict__ masksAll,
        const float* __restrict__ mxp, const float* __restrict__ Mxp,
        const float* __restrict__ cfr, float* __restrict__ G,
        const float* __restrict__ zpg)
{
    __shared__ __align__(16) float FLf[LDS_F];
    const int cls = blockIdx.x;
    const int z0  = blockIdx.y * ZT;
    const int y0  = blockIdx.z * 16;
    const int tid = threadIdx.x;
    const int lane = tid & 63, wid = tid >> 6;
    const int y  = tid >> 3;          // 0..15
    const int xg = tid & 7;           // 0..7
    const int x0 = xg * 4;
    const bool lo_inv = (xg == 0), hi_inv = (xg == 7);
    const float* mk   = masksAll + (size_t)cls * VOX;
    const float* wcls = cfr + cls*1029;          // uniform -> scalar loads
    float* Gc = G + (size_t)cls * VOX;

    issue_slice(mk, mxp, Mxp, zpg, FLf, 0,     z0-3, y0, lane, wid);
    issue_slice(mk, mxp, Mxp, zpg, FLf, BUF_F, z0-2, y0, lane, wid);

    float4 a0{},a1{},a2{},a3{},a4{},a5{},a6{};
    int cur = 0;

    #pragma unroll 1
    for (int zi = z0 - 3; zi <= z0 + ZT + 2; ++zi){
        // exact wait: leave next slice's loads (+1 store if last phase stored) in flight
        const bool pst = (zi >= z0 + 4);
        if (wid == 0){ if (pst) asm volatile("s_waitcnt vmcnt(6)" ::: "memory");
                       else     asm volatile("s_waitcnt vmcnt(5)" ::: "memory"); }
        else         { if (pst) asm volatile("s_waitcnt vmcnt(5)" ::: "memory");
                       else     asm volatile("s_waitcnt vmcnt(4)" ::: "memory"); }
        __builtin_amdgcn_sched_barrier(0);
        __builtin_amdgcn_s_barrier();
        __builtin_amdgcn_sched_barrier(0);

        const int lo = z0 + 3 - zi;                // okJ: J>=lo && J-lo<ZT (wave-uniform)
        const bool ok0 = (0>=lo) && (0-lo<ZT);
        const bool ok1 = (1>=lo) && (1-lo<ZT);
        const bool ok2 = (2>=lo) && (2-lo<ZT);
        const bool ok3 = (3>=lo) && (3-lo<ZT);
        const bool ok4 = (4>=lo) && (4-lo<ZT);
        const bool ok5 = (5>=lo) && (5-lo<ZT);
        const bool ok6 = (6>=lo) && (6-lo<ZT);

        #pragma unroll 1
        for (int dy = 0; dy < 7; ++dy){
            const int r   = y + dy;
            const int key = r & 7;
            const float* Pm = FLf + cur*BUF_F + r*32;
            const float* Pa = Pm + PLANE_F;
            const float* Pb = Pa + PLANE_F;
            const int q0 = xg > 0 ? xg-1 : 0;
            const int q2 = xg < 7 ? xg+1 : 7;
            const int c0 = (q0 ^ key)*4;
            const int c1 = (xg ^ key)*4;
            const int c2 = (q2 ^ key)*4;
            const float4 M0 = *(const float4*)(Pm + c0);
            const float4 M1 = *(const float4*)(Pm + c1);
            const float4 M2 = *(const float4*)(Pm + c2);
            const float pm0 = lo_inv ? 0.f : M0.y;
            const float pm1 = lo_inv ? 0.f : M0.z;
            const float pm2 = lo_inv ? 0.f : M0.w;
            const float pm3 = M1.x, pm4 = M1.y, pm5 = M1.z, pm6 = M1.w;
            const float pm7 = hi_inv ? 0.f : M2.x;
            const float pm8 = hi_inv ? 0.f : M2.y;
            const float pm9 = hi_inv ? 0.f : M2.z;

            {   // t = 0: field mask*mx
                const float4 A0 = *(const float4*)(Pa + c0);
                const float4 A1 = *(const float4*)(Pa + c1);
                const float4 A2 = *(const float4*)(Pa + c2);
                const float pa0 = pm0*A0.y, pa1 = pm1*A0.z, pa2 = pm2*A0.w;
                const float pa3 = pm3*A1.x, pa4 = pm4*A1.y, pa5 = pm5*A1.z, pa6 = pm6*A1.w;
                const float pa7 = pm7*A2.x, pa8 = pm8*A2.y, pa9 = pm9*A2.z;
                TGROUP4(pa, wcls)
            }
            {   // t = 1: field mask*Mx
                const float4 B0 = *(const float4*)(Pb + c0);
                const float4 B1 = *(const float4*)(Pb + c1);
                const float4 B2 = *(const float4*)(Pb + c2);
                const float pb0 = pm0*B0.y, pb1 = pm1*B0.z, pb2 = pm2*B0.w;
                const float pb3 = pm3*B1.x, pb4 = pm4*B1.y, pb5 = pm5*B1.z, pb6 = pm6*B1.w;
                const float pb7 = pm7*B2.x, pb8 = pm8*B2.y, pb9 = pm9*B2.z;
                TGROUP4(pb, wcls + 343)
            }
            // t = 2: field mask
            TGROUP4(pm, wcls + 686)
        }

        __builtin_amdgcn_sched_barrier(0);
        __builtin_amdgcn_s_barrier();            // all waves done reading buf[cur]
        __builtin_amdgcn_sched_barrier(0);
        issue_slice(mk, mxp, Mxp, zpg, FLf, cur*BUF_F, zi+2, y0, lane, wid);

        if (zi >= z0 + 3){                       // store AFTER loads (vmcnt order: [loads, store])
            const int oidx = ((zi-3)*HH + (y0 + y))*WW + x0;
            *(float4*)(Gc + oidx) = a0;
        }
        a0=a1; a1=a2; a2=a3; a3=a4; a4=a5; a5=a6;
        a6 = make_float4(0.f,0.f,0.f,0.f);
        cur ^= 1;
    }
    asm volatile("s_waitcnt vmcnt(0)" ::: "memory");  // drain dummy DMA before LDS dealloc
}

// ---- sigmoid + heat min/max + ma write (BW-bound finalize of conv) ----
__global__ __launch_bounds__(256) void k_heat(const float* __restrict__ masks,
        const float* __restrict__ mx, float* G, unsigned* __restrict__ keys)
{
    __shared__ float r4[8];
    const int i = blockIdx.y;
    const int tid = threadIdx.x;
    const size_t v4 = (size_t)blockIdx.x*256 + tid;
    float4 acc = ((const float4*)(G + (size_t)i*VOX))[v4];
    float4 m4  = ((const float4*)(masks + (size_t)i*VOX))[v4];
    float4 x4  = ((const float4*)mx)[v4];
    float4 ma;
    ma.x = m4.x/(1.f + expf(-acc.x));
    ma.y = m4.y/(1.f + expf(-acc.y));
    ma.z = m4.z/(1.f + expf(-acc.z));
    ma.w = m4.w/(1.f + expf(-acc.w));
    ((float4*)(G + (size_t)i*VOX))[v4] = ma;
    float h0 = ma.x*x4.x, h1 = ma.y*x4.y, h2 = ma.z*x4.z, h3 = ma.w*x4.w;
    float hmn = fminf(fminf(h0,h1), fminf(h2,h3));
    float hmx = fmaxf(fmaxf(h0,h1), fmaxf(h2,h3));
    #pragma unroll
    for (int off = 32; off > 0; off >>= 1){
        hmn = fminf(hmn, __shfl_xor(hmn, off));
        hmx = fmaxf(hmx, __shfl_xor(hmx, off));
    }
    if ((tid & 63) == 0){ r4[(tid>>6)*2] = hmn; r4[(tid>>6)*2+1] = hmx; }
    __syncthreads();
    if (tid == 0){
        float a = fminf(fminf(r4[0],r4[2]), fminf(r4[4],r4[6]));
        float b = fmaxf(fmaxf(r4[1],r4[3]), fmaxf(r4[5],r4[7]));
        atomicMin(&keys[i],     keyOf(a));
        atomicMax(&keys[NCL+i], keyOf(b));
    }
}

__global__ void k_thr(const unsigned* __restrict__ keys, float* __restrict__ hminA,
                      float* __restrict__ invR){
    int i = threadIdx.x;
    if (i < NCL){
        float hm = keyInv(keys[i]);
        float hM = keyInv(keys[NCL+i]);
        hminA[i] = hm;
        invR[i] = 1.f/(hM - hm);
    }
}

// ---- g = ma * (norm > 0.2), in place ----
__global__ __launch_bounds__(256) void k_region(float* G, const float* __restrict__ mx,
        const float* __restrict__ hminA, const float* __restrict__ invR)
{
    int i = blockIdx.y;
    int v = blockIdx.x*256 + threadIdx.x;
    float ma = G[i*VOX + v];
    float heat = ma * mx[v];
    float norm = (heat - hminA[i]) * invR[i];
    G[i*VOX + v] = (norm > THRESV) ? ma : 0.f;
}

// ---- per-(class,channel) sums S1 = sum x*g, S2 = sum (x*g)^2 ----
__global__ __launch_bounds__(256) void k_stats(const float* __restrict__ x,
        const float* G, float* __restrict__ part)
{
    int tid = threadIdx.x;
    int c = tid & 63, vg = tid >> 6;
    int v0 = blockIdx.x * 2048;
    float s1[NCL], s2[NCL];
    #pragma unroll
    for (int i=0;i<NCL;i++){ s1[i]=0.f; s2[i]=0.f; }
    const float* xc = x + c*VOX;
    for (int k=0;k<512;k++){
        int v = v0 + (k<<2) + vg;
        float xv = xc[v];
        #pragma unroll
        for (int i=0;i<NCL;i++){
            float p = xv * G[i*VOX + v];
            s1[i] += p;
            s2[i] = fmaf(p, p, s2[i]);
        }
    }
    __shared__ float red[4][64][2*NCL];
    #pragma unroll
    for (int i=0;i<NCL;i++){ red[vg][c][i] = s1[i]; red[vg][c][NCL+i] = s2[i]; }
    __syncthreads();
    if (vg == 0){
        float* dst = part + (size_t)blockIdx.x * (NCL*CCH*2);
        for (int i=0;i<NCL;i++){
            float a = red[0][c][i]+red[1][c][i]+red[2][c][i]+red[3][c][i];
            float b = red[0][c][NCL+i]+red[1][c][NCL+i]+red[2][c][NCL+i]+red[3][c][NCL+i];
            dst[i*CCH*2 + c*2 + 0] = a;
            dst[i*CCH*2 + c*2 + 1] = b;
        }
    }
}

// ---- finish stats: a = gamma*rinv, kc = beta - m*rinv*gamma ----
__global__ void k_params(const float* __restrict__ part, const float* __restrict__ gamma,
        const float* __restrict__ beta, float* __restrict__ aArr, float* __restrict__ kcArr)
{
    int i = blockIdx.x, c = threadIdx.x;
    float s1 = 0.f, s2 = 0.f;
    for (int b=0;b<256;b++){
        const float* p = part + (size_t)b*(NCL*CCH*2) + i*CCH*2 + c*2;
        s1 += p[0]; s2 += p[1];
    }
    float m   = s1 * (1.f/(float)VOX);
    float var = s2 * (1.f/(float)VOX) - m*m;
    float rinv = 1.f/sqrtf(var + EPSV);
    float gm = gamma[c];
    aArr[i*CCH + c]  = gm*rinv;
    kcArr[i*CCH + c] = beta[c] - m*rinv*gm;
}

__global__ void k_kcol(const float* __restrict__ kcArr, float* __restrict__ KcA){
    int c = threadIdx.x;
    if (c < CCH){
        float s = 0.f;
        for (int i=0;i<NCL;i++) s += kcArr[i*CCH + c];
        KcA[c] = s;
    }
}

// ---- final: out[c,v] = relu( x*Sum_i g_i*a_ic + K[c] ), in-place over d_out ----
__global__ __launch_bounds__(256) void k_final(const float* __restrict__ x,
        float* outAll, const float* __restrict__ aArr, const float* __restrict__ KcA)
{
    __shared__ float aL[NCL*CCH];
    __shared__ float KL[CCH];
    int tid = threadIdx.x;
    for (int q=tid; q<NCL*CCH; q+=256) aL[q] = aArr[q];
    if (tid < CCH) KL[tid] = KcA[tid];
    __syncthreads();
    int v = blockIdx.x*256 + tid;
    const float* Gp = outAll + (size_t)NCL*VOX;
    float g[NCL];
    #pragma unroll
    for (int i=0;i<NCL;i++) g[i] = Gp[i*VOX + v];
    #pragma unroll 4
    for (int c=0;c<CCH;c++){
        float P = 0.f;
        #pragma unroll
        for (int i=0;i<NCL;i++) P = fmaf(g[i], aL[i*CCH + c], P);
        float xv = x[c*VOX + v];
        outAll[c*VOX + v] = fmaxf(0.f, fmaf(xv, P, KL[c]));
    }
}

extern "C" void kernel_launch(void* const* d_in, const int* in_sizes, int n_in,
                              void* d_out, int out_size, void* d_ws, size_t ws_size,
                              hipStream_t stream)
{
    const float* x     = (const float*)d_in[0];
    const float* clsw  = (const float*)d_in[1];
    const float* clsb  = (const float*)d_in[2];
    const float* cfr   = (const float*)d_in[3];
    const float* gamma = (const float*)d_in[4];
    const float* beta  = (const float*)d_in[5];

    float* out   = (float*)d_out;
    float* logit = out + (size_t)CCH*VOX;     // second output
    float* masks = out;                       // scratch: out[0 .. 20V)
    float* G     = out + (size_t)NCL*VOX;     // scratch: out[20V .. 40V)

    float* ws    = (float*)d_ws;
    float* mxp   = ws;                        // V
    float* Mxp   = ws + VOX;                  // V
    unsigned* keys = (unsigned*)(ws + 2*(size_t)VOX);   // 40
    float* hminA = ws + 2*(size_t)VOX + 64;   // 20
    float* invR  = hminA + NCL;               // 20
    float* part  = ws + 2*(size_t)VOX + 128;  // 256*2560
    float* aArr  = part + 256*(NCL*CCH*2);    // 1280
    float* kcArr = aArr + NCL*CCH;            // 1280
    float* KcA   = kcArr + NCL*CCH;           // 64
    float* zpg   = KcA + CCH;                 // 256 (zero page for OOB lanes)

    k_init<<<1, 64, 0, stream>>>(keys, zpg);
    k_logit_softmax<<<VOX/256, 256, 0, stream>>>(x, clsw, clsb, masks, logit, mxp, Mxp);
    k_conv7<<<dim3(NCL, 8, 8), 128, 0, stream>>>(masks, mxp, Mxp, cfr, G, zpg);
    k_heat<<<dim3(VOX/1024, NCL), 256, 0, stream>>>(masks, mxp, G, keys);
    k_thr<<<1, 32, 0, stream>>>(keys, hminA, invR);
    k_region<<<dim3(VOX/256, NCL), 256, 0, stream>>>(G, mxp, hminA, invR);
    k_stats<<<256, 256, 0, stream>>>(x, G, part);
    k_params<<<NCL, CCH, 0, stream>>>(part, gamma, beta, aArr, kcArr);
    k_kcol<<<1, CCH, 0, stream>>>(kcArr, KcA);
    k_final<<<VOX/256, 256, 0, stream>>>(x, out, aArr, KcA);
}